// Round 21
// baseline (38.726 us; speedup 1.0000x reference)
//
#include <hip/hip_runtime.h>

#define E_TOTAL 262144
#define TPB 512
#define NBLK 512
#define CHUNK 512
#define MAXT 48              // max 16-pair tiles per chunk (hard bound 47)
#define W0R 24               // sW0 row stride (shorts): 48B -> 2-way banks, 16B aligned
#define W0T (32*W0R)         // 768 shorts per type
#define FNR 24               // sfn pair stride (shorts)
#define W1R 40               // sW1 n stride (shorts): 80B -> 2-way banks, 8B aligned
#define W1T (8*W1R)          // 320 shorts per type
#define NBLK2 256            // bn2f blocks

typedef __attribute__((ext_vector_type(8))) short short8;
typedef __attribute__((ext_vector_type(4))) float f32x4;

__device__ __forceinline__ float silu_f(float x) { return x / (1.0f + __expf(-x)); }

// RNE float -> bf16 bits
__device__ __forceinline__ short f2bf(float f) {
    unsigned int u = __float_as_uint(f);
    u += 0x7fffu + ((u >> 16) & 1u);
    return (short)(u >> 16);
}
__device__ __forceinline__ float bf2f(short s) {
    return __uint_as_float(((unsigned int)(unsigned short)s) << 16);
}

// Each block: ballot-sort its 512-pair chunk by type, build <=47 16-pair tiles,
// stage W0/W1/fn as bf16 in LDS (padded strides -> 2-way banks = free), MFMA
// per tile (bijective k-slot packing, HW-verified).
// PHASE 0: stages fn fp32->bf16 AND publishes the bf16 bits to gfnb (linear,
//          coalesced); 2 MFMAs/tile; BN1 stats -> partial.
// PHASE 1: loads fn as bf16 from gfnb (half the bytes, no conversion);
//          vectorized in-kernel fold of p1 -> BN1 affine; recompute C1,
//          affine+SiLU in-register, repack as B2 (A2 uses hi*4 labels), MFMA2;
//          write pre-BN2 o2 bf16; BN2 stats -> partial.
template<int PHASE>
__global__ __launch_bounds__(TPB, 4)
void nep_main(const int* __restrict__ ij, const float* __restrict__ fn,
              const float* __restrict__ W0, const float* __restrict__ W1,
              const float* __restrict__ g1, const float* __restrict__ b1,
              const int* __restrict__ norm, const float* __restrict__ p1g,
              short* __restrict__ gfnb,
              float* __restrict__ partial, short* __restrict__ o2b)
{
    __shared__ __align__(16) short sW0[16 * W0T];                    // 24KB
    __shared__ __align__(16) short sW1[(PHASE == 1) ? 16 * W1T : 8]; // 10KB
    __shared__ __align__(16) short sfn[CHUNK * FNR];                 // 24KB
    __shared__ int whist[8][16];
    __shared__ int woff[8][16];
    __shared__ int soff[16];
    __shared__ int tstart[17];
    __shared__ short slotp[MAXT * 16];   // tile slot -> local pair (-1 pad)
    __shared__ char ttype[MAXT];
    __shared__ float rS[8][32], rQ[8][32];
    __shared__ float fred[(PHASE == 1) ? 32 * 64 : 8];
    __shared__ float sAB1[64];

    const int tid  = threadIdx.x;
    const int bid  = blockIdx.x;
    const int l    = tid & 63;
    const int wave = tid >> 6;           // 0..7
    const int p    = l & 15;             // pair column within tile
    const int hi   = l >> 4;             // k-slot / row group
    const int base = bid * CHUNK;

    // ---- issue ALL independent global loads up front ----
    const int t0 = ij[base + tid];
    float4 u0, u1, u2, u3;
    short8 fb0, fb1;
    if constexpr (PHASE == 0) {
        const float4* f4g = (const float4*)(fn + (size_t)(base + tid) * 16);
        u0 = f4g[0]; u1 = f4g[1]; u2 = f4g[2]; u3 = f4g[3];
    } else {
        const short8* g8 = (const short8*)(gfnb + (size_t)(base + tid) * 16);
        fb0 = g8[0]; fb1 = g8[1];
    }
    const float4* W04 = (const float4*)W0;
    float4 w0v0 = W04[tid],            w0v1 = W04[tid + TPB];
    float4 w0v2 = W04[tid + 2 * TPB],  w0v3 = W04[tid + 3 * TPB];
    float4 w1v0, w1v1;
    if constexpr (PHASE == 1) {
        const float4* W14 = (const float4*)W1;
        w1v0 = W14[tid]; w1v1 = W14[tid + TPB];
    }

    // ---- ballot multi-split sort (stable: wave-major, lane-major) ----
    unsigned long long bl0 = __ballot(t0 & 1);
    unsigned long long bl1 = __ballot(t0 & 2);
    unsigned long long bl2 = __ballot(t0 & 4);
    unsigned long long bl3 = __ballot(t0 & 8);
    unsigned long long mself = ((t0 & 1) ? bl0 : ~bl0) & ((t0 & 2) ? bl1 : ~bl1)
                             & ((t0 & 4) ? bl2 : ~bl2) & ((t0 & 8) ? bl3 : ~bl3);
    const int rank_w = __popcll(mself & ((1ull << l) - 1ull));
    if (l < 16) {
        const int t = l;
        unsigned long long mt = ((t & 1) ? bl0 : ~bl0) & ((t & 2) ? bl1 : ~bl1)
                              & ((t & 4) ? bl2 : ~bl2) & ((t & 8) ? bl3 : ~bl3);
        whist[wave][t] = __popcll(mt);
    }
    if (tid < MAXT * 16 / 2) ((int*)slotp)[tid] = -1;

    // ---- stage W0 (bf16, padded rows) from pre-loaded regs ----
    {
        #pragma unroll
        for (int i = 0; i < 4; i++) {
            float4 v = (i == 0) ? w0v0 : (i == 1) ? w0v1 : (i == 2) ? w0v2 : w0v3;
            int g = (tid + i * TPB) * 4;
            int t = g >> 9, h = (g >> 4) & 31, k0 = g & 15;
            short4 s;
            s.x = f2bf(v.x); s.y = f2bf(v.y); s.z = f2bf(v.z); s.w = f2bf(v.w);
            *(short4*)(sW0 + t * W0T + h * W0R + k0) = s;
        }
    }
    if constexpr (PHASE == 1) {
        #pragma unroll
        for (int i = 0; i < 2; i++) {
            float4 v = (i == 0) ? w1v0 : w1v1;
            int g = (tid + i * TPB) * 4;
            int t = g >> 8, n = (g >> 5) & 7, h0 = g & 31;
            short4 s;
            s.x = f2bf(v.x); s.y = f2bf(v.y); s.z = f2bf(v.z); s.w = f2bf(v.w);
            *(short4*)(sW1 + t * W1T + n * W1R + h0) = s;
        }
    }
    // ---- stage fn into LDS; PHASE 0 also publishes bf16 bits to gfnb ----
    if constexpr (PHASE == 0) {
        short8 w0, w1;
        w0[0]=f2bf(u0.x); w0[1]=f2bf(u0.y); w0[2]=f2bf(u0.z); w0[3]=f2bf(u0.w);
        w0[4]=f2bf(u1.x); w0[5]=f2bf(u1.y); w0[6]=f2bf(u1.z); w0[7]=f2bf(u1.w);
        w1[0]=f2bf(u2.x); w1[1]=f2bf(u2.y); w1[2]=f2bf(u2.z); w1[3]=f2bf(u2.w);
        w1[4]=f2bf(u3.x); w1[5]=f2bf(u3.y); w1[6]=f2bf(u3.z); w1[7]=f2bf(u3.w);
        *(short8*)(sfn + tid * FNR)     = w0;
        *(short8*)(sfn + tid * FNR + 8) = w1;
        short8* g8 = (short8*)(gfnb + (size_t)(base + tid) * 16);
        g8[0] = w0; g8[1] = w1;
    } else {
        *(short8*)(sfn + tid * FNR)     = fb0;
        *(short8*)(sfn + tid * FNR + 8) = fb1;
    }
    // ---- PHASE 1: p1 fold partial — float4 over channels, paired accs ----
    if constexpr (PHASE == 1) {
        const int q = tid & 15;          // channel quad
        const int j = tid >> 4;          // stripe 0..31
        float4 sa = {0.f,0.f,0.f,0.f}, sb = {0.f,0.f,0.f,0.f};
        #pragma unroll
        for (int m = 0; m < 16; m += 2) {
            float4 a = *(const float4*)(p1g + (j + 32 * m) * 64 + q * 4);
            float4 b = *(const float4*)(p1g + (j + 32 * (m + 1)) * 64 + q * 4);
            sa.x += a.x; sa.y += a.y; sa.z += a.z; sa.w += a.w;
            sb.x += b.x; sb.y += b.y; sb.z += b.z; sb.w += b.w;
        }
        float4 s;
        s.x = sa.x + sb.x; s.y = sa.y + sb.y; s.z = sa.z + sb.z; s.w = sa.w + sb.w;
        *(float4*)(fred + j * 64 + q * 4) = s;
    }
    __syncthreads();

    // ---- block-level type offsets (8-wave prefix) + fold reduce ----
    if (tid < 16) {
        int acc = 0;
        #pragma unroll
        for (int w = 0; w < 8; w++) { woff[w][tid] = acc; acc += whist[w][tid]; }
        soff[tid] = acc;
    }
    if constexpr (PHASE == 1) {
        if (tid >= 64 && tid < 128) {
            const int c = tid - 64;
            float q0 = 0.f, q1 = 0.f, q2 = 0.f, q3 = 0.f;
            #pragma unroll
            for (int jj = 0; jj < 32; jj += 4) {
                q0 += fred[jj * 64 + c];
                q1 += fred[(jj + 1) * 64 + c];
                q2 += fred[(jj + 2) * 64 + c];
                q3 += fred[(jj + 3) * 64 + c];
            }
            fred[c] = (q0 + q1) + (q2 + q3);
        }
    }
    __syncthreads();
    // parallel exclusive scan of tile counts (wave 0) + BN1 affine (wave 2)
    if (tid < 16) {
        int nt = (soff[tid] + 15) >> 4;
        int inc = nt;
        #pragma unroll
        for (int off = 1; off < 16; off <<= 1) {
            int v = __shfl_up(inc, off, 64);
            if (tid >= off) inc += v;
        }
        tstart[tid] = inc - nt;
        if (tid == 15) tstart[16] = inc;
    }
    if constexpr (PHASE == 1) {
        if (tid >= 128 && tid < 160) {
            const int c = tid - 128;
            const float invE = 1.0f / (float)E_TOTAL;
            float mean = fred[c] * invE;
            float var  = fred[32 + c] * invE - mean * mean;
            float inv  = rsqrtf(var + 1e-5f);
            float a, b;
            if (*norm) { a = g1[c] * inv; b = b1[c] - mean * a; }
            else       { a = 1.f; b = 0.f; }
            sAB1[c]      = a;
            sAB1[32 + c] = b;
        }
    }
    __syncthreads();
    {
        const int rank = woff[wave][t0] + rank_w;
        const int ti = tstart[t0] + (rank >> 4);
        slotp[ti * 16 + (rank & 15)] = (short)tid;
        ttype[ti] = (char)t0;                 // same-value races benign
    }
    __syncthreads();
    const int ntiles = tstart[16];            // <= 47

    float a1r[4], b1r[4], a1R[4], b1R[4];
    if constexpr (PHASE == 1) {
        #pragma unroll
        for (int r = 0; r < 4; r++) {
            a1r[r] = sAB1[hi * 4 + r];      b1r[r] = sAB1[32 + hi * 4 + r];
            a1R[r] = sAB1[16 + hi * 4 + r]; b1R[r] = sAB1[48 + hi * 4 + r];
        }
    }

    float s1[8], s2[8];
    #pragma unroll
    for (int c = 0; c < 8; c++) { s1[c] = 0.f; s2[c] = 0.f; }

    // ---- tile loop: wave handles tiles wave, wave+8, ... (predicated, x2) ----
    #pragma unroll 2
    for (int it = 0; it < 6; it++) {
        const int ti = wave + it * 8;
        const bool tv = (ti < ntiles);
        const int t  = tv ? (int)ttype[ti] : 0;
        const int sp = tv ? (int)slotp[ti * 16 + p] : -1;
        const bool vs = (sp >= 0);

        short8 bF = {0,0,0,0,0,0,0,0};
        if (hi < 2 && vs)
            bF = *(const short8*)(sfn + sp * FNR + hi * 8);
        // A loads unconditional; hh valid ONLY for MFMA1 (B's hi>=2 slots zero).
        const int hh = hi & 1;
        short8 a0 = *(const short8*)(sW0 + t * W0T + p * W0R + hh * 8);
        short8 a1 = *(const short8*)(sW0 + t * W0T + 16 * W0R + p * W0R + hh * 8);
        f32x4 z = {0.f, 0.f, 0.f, 0.f};
        f32x4 c0 = __builtin_amdgcn_mfma_f32_16x16x32_bf16(a0, bF, z, 0, 0, 0);
        f32x4 c1 = __builtin_amdgcn_mfma_f32_16x16x32_bf16(a1, bF, z, 0, 0, 0);
        // c0[r] = out1[hi*4+r][p], c1[r] = out1[16+hi*4+r][p]

        if constexpr (PHASE == 0) {
            if (tv) {
                #pragma unroll
                for (int r = 0; r < 4; r++) {
                    s1[r]     += c0[r]; s2[r]     += c0[r] * c0[r];
                    s1[4 + r] += c1[r]; s2[4 + r] += c1[r] * c1[r];
                }
            }
        } else {
            short8 bS;
            #pragma unroll
            for (int r = 0; r < 4; r++) {
                float x0 = a1r[r] * c0[r] + b1r[r];
                float x1 = a1R[r] * c1[r] + b1R[r];
                bS[r]     = f2bf(vs ? silu_f(x0) : 0.f);
                bS[4 + r] = f2bf(vs ? silu_f(x1) : 0.f);
            }
            // A2 MUST use hi*4 labels: bS carries data in ALL hi-groups.
            short8 a2v = {0,0,0,0,0,0,0,0};
            if (p < 8) {
                short4 A = *(const short4*)(sW1 + t * W1T + p * W1R + hi * 4);
                short4 B = *(const short4*)(sW1 + t * W1T + p * W1R + 16 + hi * 4);
                a2v[0] = A.x; a2v[1] = A.y; a2v[2] = A.z; a2v[3] = A.w;
                a2v[4] = B.x; a2v[5] = B.y; a2v[6] = B.z; a2v[7] = B.w;
            }
            f32x4 c2 = __builtin_amdgcn_mfma_f32_16x16x32_bf16(a2v, bS, z, 0, 0, 0);
            if (hi < 2 && vs) {
                short4 s;
                s.x = f2bf(c2[0]); s.y = f2bf(c2[1]); s.z = f2bf(c2[2]); s.w = f2bf(c2[3]);
                *(short4*)(o2b + (size_t)(base + sp) * 8 + hi * 4) = s;
            }
            if (tv) {
                #pragma unroll
                for (int r = 0; r < 4; r++) { s1[r] += c2[r]; s2[r] += c2[r] * c2[r]; }
            }
        }
    }

    // ---- reduce over pair columns p ----
    constexpr int NC = (PHASE == 0) ? 8 : 4;
    #pragma unroll
    for (int c = 0; c < NC; c++) {
        float v1 = s1[c], v2 = s2[c];
        v1 += __shfl_xor(v1, 1, 64); v2 += __shfl_xor(v2, 1, 64);
        v1 += __shfl_xor(v1, 2, 64); v2 += __shfl_xor(v2, 2, 64);
        v1 += __shfl_xor(v1, 4, 64); v2 += __shfl_xor(v2, 4, 64);
        v1 += __shfl_xor(v1, 8, 64); v2 += __shfl_xor(v2, 8, 64);
        s1[c] = v1; s2[c] = v2;
    }
    if constexpr (PHASE == 0) {
        if (p == 0) {
            #pragma unroll
            for (int r = 0; r < 4; r++) {
                rS[wave][hi * 4 + r]      = s1[r];     rQ[wave][hi * 4 + r]      = s2[r];
                rS[wave][16 + hi * 4 + r] = s1[4 + r]; rQ[wave][16 + hi * 4 + r] = s2[4 + r];
            }
        }
        __syncthreads();
        if (tid < 32) {
            float a = 0.f, b = 0.f;
            #pragma unroll
            for (int w = 0; w < 8; w++) { a += rS[w][tid]; b += rQ[w][tid]; }
            partial[bid * 64 + tid]      = a;
            partial[bid * 64 + 32 + tid] = b;
        }
    } else {
        if (p == 0 && hi < 2) {
            #pragma unroll
            for (int r = 0; r < 4; r++) {
                rS[wave][hi * 4 + r] = s1[r];
                rQ[wave][hi * 4 + r] = s2[r];
            }
        }
        __syncthreads();
        if (tid < 8) {
            float a = 0.f, b = 0.f;
            #pragma unroll
            for (int w = 0; w < 8; w++) { a += rS[w][tid]; b += rQ[w][tid]; }
            partial[bid * 16 + tid]     = a;
            partial[bid * 16 + 8 + tid] = b;
        }
    }
}

// ---- fused BN2 finalize + streaming epilogue (256 blocks x 4 stripes) ----
__global__ __launch_bounds__(256)
void nep_bn2f(const short* __restrict__ o2b, const float* __restrict__ p2,
              const float* __restrict__ gamma, const float* __restrict__ beta,
              const int* __restrict__ norm, float* __restrict__ out)
{
    __shared__ float ssum[16][16];
    __shared__ float sA[8], sB[8];
    const int tid = threadIdx.x;
    {
        const int cc = tid & 15;
        const int j  = tid >> 4;
        float q0 = 0.f, q1 = 0.f;
        for (int blk = j; blk < NBLK; blk += 32) {
            q0 += p2[blk * 16 + cc];
            q1 += p2[(blk + 16) * 16 + cc];
        }
        ssum[j][cc] = q0 + q1;
    }
    __syncthreads();
    if (tid < 16) {
        float t = 0.f;
        #pragma unroll
        for (int jj = 0; jj < 16; jj++) t += ssum[jj][tid];
        ssum[0][tid] = t;
    }
    __syncthreads();
    if (tid < 8) {
        const float invE = 1.0f / (float)E_TOTAL;
        float mean = ssum[0][tid] * invE;
        float var  = ssum[0][8 + tid] * invE - mean * mean;
        float inv  = rsqrtf(var + 1e-5f);
        float a, b;
        if (*norm) { a = gamma[tid] * inv; b = beta[tid] - mean * a; }
        else       { a = 1.f; b = 0.f; }
        sA[tid] = a; sB[tid] = b;
    }
    __syncthreads();
    float a0 = sA[0], a1 = sA[1], a2 = sA[2], a3 = sA[3];
    float a4 = sA[4], a5 = sA[5], a6 = sA[6], a7 = sA[7];
    float b0 = sB[0], b1 = sB[1], b2 = sB[2], b3 = sB[3];
    float b4 = sB[4], b5 = sB[5], b6 = sB[6], b7 = sB[7];
    #pragma unroll
    for (int r = 0; r < 4; r++) {
        const int e = blockIdx.x * 256 + tid + r * (NBLK2 * 256);
        short8 v = *(const short8*)(o2b + (size_t)e * 8);
        float4 o0, o1;
        o0.x = silu_f(a0 * bf2f(v[0]) + b0);
        o0.y = silu_f(a1 * bf2f(v[1]) + b1);
        o0.z = silu_f(a2 * bf2f(v[2]) + b2);
        o0.w = silu_f(a3 * bf2f(v[3]) + b3);
        o1.x = silu_f(a4 * bf2f(v[4]) + b4);
        o1.y = silu_f(a5 * bf2f(v[5]) + b5);
        o1.z = silu_f(a6 * bf2f(v[6]) + b6);
        o1.w = silu_f(a7 * bf2f(v[7]) + b7);
        *(float4*)(out + (size_t)e * 8)     = o0;
        *(float4*)(out + (size_t)e * 8 + 4) = o1;
    }
}

extern "C" void kernel_launch(void* const* d_in, const int* in_sizes, int n_in,
                              void* d_out, int out_size, void* d_ws, size_t ws_size,
                              hipStream_t stream)
{
    const int*   ij   = (const int*)d_in[0];
    const float* fn   = (const float*)d_in[1];
    const float* W0   = (const float*)d_in[2];
    const float* W1   = (const float*)d_in[3];
    const float* g1   = (const float*)d_in[4];
    const float* b1   = (const float*)d_in[5];
    const float* g2   = (const float*)d_in[6];
    const float* b2   = (const float*)d_in[7];
    const int*   norm = (const int*)d_in[8];
    float* out = (float*)d_out;

    float* p1   = (float*)d_ws;              // 512*64
    float* p2   = p1 + NBLK * 64;            // 512*16
    short* o2b  = (short*)(p2 + NBLK * 16);  // E*8 bf16 (4 MB)
    short* gfnb = o2b + (size_t)E_TOTAL * 8; // E*16 bf16 (8 MB)

    nep_main<0><<<NBLK, TPB, 0, stream>>>(ij, fn, W0, W1, g1, b1, norm, nullptr,
                                          gfnb, p1, nullptr);
    nep_main<1><<<NBLK, TPB, 0, stream>>>(ij, fn, W0, W1, g1, b1, norm, p1,
                                          gfnb, p2, o2b);
    nep_bn2f<<<NBLK2, 256, 0, stream>>>(o2b, p2, g2, b2, norm, out);
}

// Round 22
// 37.393 us; speedup vs baseline: 1.0356x; 1.0356x over previous
//
#include <hip/hip_runtime.h>

#define E_TOTAL 262144
#define TPB 512
#define NBLK 512
#define CHUNK 512
#define MAXT 48              // max 16-pair tiles per chunk (hard bound 47)
#define W0R 24               // sW0 row stride (shorts): 48B -> 2-way banks, 16B aligned
#define W0T (32*W0R)         // 768 shorts per type
#define FNR 24               // sfn pair stride (shorts)
#define W1R 40               // sW1 n stride (shorts): 80B -> 2-way banks, 8B aligned
#define W1T (8*W1R)          // 320 shorts per type
#define NBLK2 256            // bn2f blocks

typedef __attribute__((ext_vector_type(8))) short short8;
typedef __attribute__((ext_vector_type(4))) float f32x4;

__device__ __forceinline__ float silu_f(float x) { return x / (1.0f + __expf(-x)); }

// RNE float -> bf16 bits
__device__ __forceinline__ short f2bf(float f) {
    unsigned int u = __float_as_uint(f);
    u += 0x7fffu + ((u >> 16) & 1u);
    return (short)(u >> 16);
}
__device__ __forceinline__ float bf2f(short s) {
    return __uint_as_float(((unsigned int)(unsigned short)s) << 16);
}

// Each block: ballot-sort its 512-pair chunk by type, build <=47 16-pair tiles,
// stage W0/W1/fn as bf16 in LDS (padded strides: tile-loop ds_reads 2-way bank
// coverage = free), MFMA per tile (bijective k-slot packing, HW-verified).
// PHASE 0: C1 = W0[t] @ fn (2 MFMAs/tile); BN1 sum/sumsq -> partial.
// PHASE 1: vectorized ILP fold of p1 -> BN1 affine in-kernel, recompute C1,
//          BN1 affine + SiLU in-register, repack as B2 (A2 uses hi*4 labels),
//          MFMA2; write pre-BN2 o2 bf16; BN2 stats -> partial.
template<int PHASE>
__global__ __launch_bounds__(TPB, 4)
void nep_main(const int* __restrict__ ij, const float* __restrict__ fn,
              const float* __restrict__ W0, const float* __restrict__ W1,
              const float* __restrict__ g1, const float* __restrict__ b1,
              const int* __restrict__ norm, const float* __restrict__ p1g,
              float* __restrict__ partial, short* __restrict__ o2b)
{
    __shared__ __align__(16) short sW0[16 * W0T];                    // 24KB
    __shared__ __align__(16) short sW1[(PHASE == 1) ? 16 * W1T : 8]; // 10KB
    __shared__ __align__(16) short sfn[CHUNK * FNR];                 // 24KB
    __shared__ int whist[8][16];
    __shared__ int woff[8][16];
    __shared__ int soff[16];
    __shared__ int tstart[17];
    __shared__ short slotp[MAXT * 16];   // tile slot -> local pair (-1 pad)
    __shared__ char ttype[MAXT];
    __shared__ float rS[8][32], rQ[8][32];
    __shared__ float fred[(PHASE == 1) ? 32 * 64 : 8];
    __shared__ float sAB1[64];

    const int tid  = threadIdx.x;
    const int bid  = blockIdx.x;
    const int l    = tid & 63;
    const int wave = tid >> 6;           // 0..7
    const int p    = l & 15;             // pair column within tile
    const int hi   = l >> 4;             // k-slot / row group
    const int base = bid * CHUNK;

    // ---- issue ALL independent global loads up front (ij, fn, W0, W1) ----
    const int t0 = ij[base + tid];
    const float4* f4g = (const float4*)(fn + (size_t)(base + tid) * 16);
    float4 u0 = f4g[0], u1 = f4g[1], u2 = f4g[2], u3 = f4g[3];
    const float4* W04 = (const float4*)W0;
    float4 w0v0 = W04[tid],            w0v1 = W04[tid + TPB];
    float4 w0v2 = W04[tid + 2 * TPB],  w0v3 = W04[tid + 3 * TPB];
    float4 w1v0, w1v1;
    if constexpr (PHASE == 1) {
        const float4* W14 = (const float4*)W1;
        w1v0 = W14[tid]; w1v1 = W14[tid + TPB];
    }

    // ---- ballot multi-split sort (stable: wave-major, lane-major) ----
    unsigned long long bl0 = __ballot(t0 & 1);
    unsigned long long bl1 = __ballot(t0 & 2);
    unsigned long long bl2 = __ballot(t0 & 4);
    unsigned long long bl3 = __ballot(t0 & 8);
    unsigned long long mself = ((t0 & 1) ? bl0 : ~bl0) & ((t0 & 2) ? bl1 : ~bl1)
                             & ((t0 & 4) ? bl2 : ~bl2) & ((t0 & 8) ? bl3 : ~bl3);
    const int rank_w = __popcll(mself & ((1ull << l) - 1ull));
    if (l < 16) {
        const int t = l;
        unsigned long long mt = ((t & 1) ? bl0 : ~bl0) & ((t & 2) ? bl1 : ~bl1)
                              & ((t & 4) ? bl2 : ~bl2) & ((t & 8) ? bl3 : ~bl3);
        whist[wave][t] = __popcll(mt);
    }
    if (tid < MAXT * 16 / 2) ((int*)slotp)[tid] = -1;

    // ---- stage W0 (bf16, padded rows) from pre-loaded regs ----
    {
        #pragma unroll
        for (int i = 0; i < 4; i++) {
            float4 v = (i == 0) ? w0v0 : (i == 1) ? w0v1 : (i == 2) ? w0v2 : w0v3;
            int g = (tid + i * TPB) * 4;
            int t = g >> 9, h = (g >> 4) & 31, k0 = g & 15;
            short4 s;
            s.x = f2bf(v.x); s.y = f2bf(v.y); s.z = f2bf(v.z); s.w = f2bf(v.w);
            *(short4*)(sW0 + t * W0T + h * W0R + k0) = s;
        }
    }
    if constexpr (PHASE == 1) {
        #pragma unroll
        for (int i = 0; i < 2; i++) {
            float4 v = (i == 0) ? w1v0 : w1v1;
            int g = (tid + i * TPB) * 4;
            int t = g >> 8, n = (g >> 5) & 7, h0 = g & 31;
            short4 s;
            s.x = f2bf(v.x); s.y = f2bf(v.y); s.z = f2bf(v.z); s.w = f2bf(v.w);
            *(short4*)(sW1 + t * W1T + n * W1R + h0) = s;
        }
    }
    // ---- stage fn (bf16, padded pair stride) ----
    {
        short8 w0, w1;
        w0[0]=f2bf(u0.x); w0[1]=f2bf(u0.y); w0[2]=f2bf(u0.z); w0[3]=f2bf(u0.w);
        w0[4]=f2bf(u1.x); w0[5]=f2bf(u1.y); w0[6]=f2bf(u1.z); w0[7]=f2bf(u1.w);
        w1[0]=f2bf(u2.x); w1[1]=f2bf(u2.y); w1[2]=f2bf(u2.z); w1[3]=f2bf(u2.w);
        w1[4]=f2bf(u3.x); w1[5]=f2bf(u3.y); w1[6]=f2bf(u3.z); w1[7]=f2bf(u3.w);
        *(short8*)(sfn + tid * FNR)     = w0;
        *(short8*)(sfn + tid * FNR + 8) = w1;
    }
    // ---- PHASE 1: p1 fold partial — float4 over channels, paired accs ----
    if constexpr (PHASE == 1) {
        const int q = tid & 15;          // channel quad (4 channels)
        const int j = tid >> 4;          // stripe 0..31
        float4 sa = {0.f,0.f,0.f,0.f}, sb = {0.f,0.f,0.f,0.f};
        #pragma unroll
        for (int m = 0; m < 16; m += 2) {
            float4 a = *(const float4*)(p1g + (j + 32 * m) * 64 + q * 4);
            float4 b = *(const float4*)(p1g + (j + 32 * (m + 1)) * 64 + q * 4);
            sa.x += a.x; sa.y += a.y; sa.z += a.z; sa.w += a.w;
            sb.x += b.x; sb.y += b.y; sb.z += b.z; sb.w += b.w;
        }
        float4 s;
        s.x = sa.x + sb.x; s.y = sa.y + sb.y; s.z = sa.z + sb.z; s.w = sa.w + sb.w;
        *(float4*)(fred + j * 64 + q * 4) = s;
    }
    __syncthreads();

    // ---- block-level type offsets (8-wave prefix) + fold reduce ----
    if (tid < 16) {
        int acc = 0;
        #pragma unroll
        for (int w = 0; w < 8; w++) { woff[w][tid] = acc; acc += whist[w][tid]; }
        soff[tid] = acc;
    }
    if constexpr (PHASE == 1) {
        if (tid >= 64 && tid < 128) {
            const int c = tid - 64;
            float q0 = 0.f, q1 = 0.f, q2 = 0.f, q3 = 0.f;
            #pragma unroll
            for (int jj = 0; jj < 32; jj += 4) {
                q0 += fred[jj * 64 + c];
                q1 += fred[(jj + 1) * 64 + c];
                q2 += fred[(jj + 2) * 64 + c];
                q3 += fred[(jj + 3) * 64 + c];
            }
            fred[c] = (q0 + q1) + (q2 + q3);
        }
    }
    __syncthreads();
    // parallel exclusive scan of tile counts (wave 0) + BN1 affine (wave 2+)
    if (tid < 16) {
        int nt = (soff[tid] + 15) >> 4;
        int inc = nt;
        #pragma unroll
        for (int off = 1; off < 16; off <<= 1) {
            int v = __shfl_up(inc, off, 64);
            if (tid >= off) inc += v;
        }
        tstart[tid] = inc - nt;
        if (tid == 15) tstart[16] = inc;
    }
    if constexpr (PHASE == 1) {
        if (tid >= 128 && tid < 160) {
            const int c = tid - 128;
            const float invE = 1.0f / (float)E_TOTAL;
            float mean = fred[c] * invE;
            float var  = fred[32 + c] * invE - mean * mean;
            float inv  = rsqrtf(var + 1e-5f);
            float a, b;
            if (*norm) { a = g1[c] * inv; b = b1[c] - mean * a; }
            else       { a = 1.f; b = 0.f; }
            sAB1[c]      = a;
            sAB1[32 + c] = b;
        }
    }
    __syncthreads();
    {
        const int rank = woff[wave][t0] + rank_w;
        const int ti = tstart[t0] + (rank >> 4);
        slotp[ti * 16 + (rank & 15)] = (short)tid;
        ttype[ti] = (char)t0;                 // same-value races benign
    }
    __syncthreads();
    const int ntiles = tstart[16];            // <= 47

    float a1r[4], b1r[4], a1R[4], b1R[4];
    if constexpr (PHASE == 1) {
        #pragma unroll
        for (int r = 0; r < 4; r++) {
            a1r[r] = sAB1[hi * 4 + r];      b1r[r] = sAB1[32 + hi * 4 + r];
            a1R[r] = sAB1[16 + hi * 4 + r]; b1R[r] = sAB1[48 + hi * 4 + r];
        }
    }

    float s1[8], s2[8];
    #pragma unroll
    for (int c = 0; c < 8; c++) { s1[c] = 0.f; s2[c] = 0.f; }

    // ---- tile loop: wave handles tiles wave, wave+8, ... (predicated, x2) ----
    #pragma unroll 2
    for (int it = 0; it < 6; it++) {
        const int ti = wave + it * 8;
        const bool tv = (ti < ntiles);
        const int t  = tv ? (int)ttype[ti] : 0;
        const int sp = tv ? (int)slotp[ti * 16 + p] : -1;
        const bool vs = (sp >= 0);

        short8 bF = {0,0,0,0,0,0,0,0};
        if (hi < 2 && vs)
            bF = *(const short8*)(sfn + sp * FNR + hi * 8);
        // A loads unconditional; hh valid ONLY for MFMA1 (B's hi>=2 slots zero).
        const int hh = hi & 1;
        short8 a0 = *(const short8*)(sW0 + t * W0T + p * W0R + hh * 8);
        short8 a1 = *(const short8*)(sW0 + t * W0T + 16 * W0R + p * W0R + hh * 8);
        f32x4 z = {0.f, 0.f, 0.f, 0.f};
        f32x4 c0 = __builtin_amdgcn_mfma_f32_16x16x32_bf16(a0, bF, z, 0, 0, 0);
        f32x4 c1 = __builtin_amdgcn_mfma_f32_16x16x32_bf16(a1, bF, z, 0, 0, 0);
        // c0[r] = out1[hi*4+r][p], c1[r] = out1[16+hi*4+r][p]

        if constexpr (PHASE == 0) {
            if (tv) {
                #pragma unroll
                for (int r = 0; r < 4; r++) {
                    s1[r]     += c0[r]; s2[r]     += c0[r] * c0[r];
                    s1[4 + r] += c1[r]; s2[4 + r] += c1[r] * c1[r];
                }
            }
        } else {
            short8 bS;
            #pragma unroll
            for (int r = 0; r < 4; r++) {
                float x0 = a1r[r] * c0[r] + b1r[r];
                float x1 = a1R[r] * c1[r] + b1R[r];
                bS[r]     = f2bf(vs ? silu_f(x0) : 0.f);
                bS[4 + r] = f2bf(vs ? silu_f(x1) : 0.f);
            }
            // A2 MUST use hi*4 labels: bS carries data in ALL hi-groups.
            short8 a2v = {0,0,0,0,0,0,0,0};
            if (p < 8) {
                short4 A = *(const short4*)(sW1 + t * W1T + p * W1R + hi * 4);
                short4 B = *(const short4*)(sW1 + t * W1T + p * W1R + 16 + hi * 4);
                a2v[0] = A.x; a2v[1] = A.y; a2v[2] = A.z; a2v[3] = A.w;
                a2v[4] = B.x; a2v[5] = B.y; a2v[6] = B.z; a2v[7] = B.w;
            }
            f32x4 c2 = __builtin_amdgcn_mfma_f32_16x16x32_bf16(a2v, bS, z, 0, 0, 0);
            if (hi < 2 && vs) {
                short4 s;
                s.x = f2bf(c2[0]); s.y = f2bf(c2[1]); s.z = f2bf(c2[2]); s.w = f2bf(c2[3]);
                *(short4*)(o2b + (size_t)(base + sp) * 8 + hi * 4) = s;
            }
            if (tv) {
                #pragma unroll
                for (int r = 0; r < 4; r++) { s1[r] += c2[r]; s2[r] += c2[r] * c2[r]; }
            }
        }
    }

    // ---- reduce over pair columns p ----
    constexpr int NC = (PHASE == 0) ? 8 : 4;
    #pragma unroll
    for (int c = 0; c < NC; c++) {
        float v1 = s1[c], v2 = s2[c];
        v1 += __shfl_xor(v1, 1, 64); v2 += __shfl_xor(v2, 1, 64);
        v1 += __shfl_xor(v1, 2, 64); v2 += __shfl_xor(v2, 2, 64);
        v1 += __shfl_xor(v1, 4, 64); v2 += __shfl_xor(v2, 4, 64);
        v1 += __shfl_xor(v1, 8, 64); v2 += __shfl_xor(v2, 8, 64);
        s1[c] = v1; s2[c] = v2;
    }
    if constexpr (PHASE == 0) {
        if (p == 0) {
            #pragma unroll
            for (int r = 0; r < 4; r++) {
                rS[wave][hi * 4 + r]      = s1[r];     rQ[wave][hi * 4 + r]      = s2[r];
                rS[wave][16 + hi * 4 + r] = s1[4 + r]; rQ[wave][16 + hi * 4 + r] = s2[4 + r];
            }
        }
        __syncthreads();
        if (tid < 32) {
            float a = 0.f, b = 0.f;
            #pragma unroll
            for (int w = 0; w < 8; w++) { a += rS[w][tid]; b += rQ[w][tid]; }
            partial[bid * 64 + tid]      = a;
            partial[bid * 64 + 32 + tid] = b;
        }
    } else {
        if (p == 0 && hi < 2) {
            #pragma unroll
            for (int r = 0; r < 4; r++) {
                rS[wave][hi * 4 + r] = s1[r];
                rQ[wave][hi * 4 + r] = s2[r];
            }
        }
        __syncthreads();
        if (tid < 8) {
            float a = 0.f, b = 0.f;
            #pragma unroll
            for (int w = 0; w < 8; w++) { a += rS[w][tid]; b += rQ[w][tid]; }
            partial[bid * 16 + tid]     = a;
            partial[bid * 16 + 8 + tid] = b;
        }
    }
}

// ---- fused BN2 finalize + streaming epilogue (256 blocks x 4 stripes) ----
__global__ __launch_bounds__(256)
void nep_bn2f(const short* __restrict__ o2b, const float* __restrict__ p2,
              const float* __restrict__ gamma, const float* __restrict__ beta,
              const int* __restrict__ norm, float* __restrict__ out)
{
    __shared__ float ssum[16][16];
    __shared__ float sA[8], sB[8];
    const int tid = threadIdx.x;
    {
        const int cc = tid & 15;
        const int j  = tid >> 4;
        float q0 = 0.f, q1 = 0.f;
        for (int blk = j; blk < NBLK; blk += 32) {
            q0 += p2[blk * 16 + cc];
            q1 += p2[(blk + 16) * 16 + cc];
        }
        ssum[j][cc] = q0 + q1;
    }
    __syncthreads();
    if (tid < 16) {
        float t = 0.f;
        #pragma unroll
        for (int jj = 0; jj < 16; jj++) t += ssum[jj][tid];
        ssum[0][tid] = t;
    }
    __syncthreads();
    if (tid < 8) {
        const float invE = 1.0f / (float)E_TOTAL;
        float mean = ssum[0][tid] * invE;
        float var  = ssum[0][8 + tid] * invE - mean * mean;
        float inv  = rsqrtf(var + 1e-5f);
        float a, b;
        if (*norm) { a = gamma[tid] * inv; b = beta[tid] - mean * a; }
        else       { a = 1.f; b = 0.f; }
        sA[tid] = a; sB[tid] = b;
    }
    __syncthreads();
    float a0 = sA[0], a1 = sA[1], a2 = sA[2], a3 = sA[3];
    float a4 = sA[4], a5 = sA[5], a6 = sA[6], a7 = sA[7];
    float b0 = sB[0], b1 = sB[1], b2 = sB[2], b3 = sB[3];
    float b4 = sB[4], b5 = sB[5], b6 = sB[6], b7 = sB[7];
    #pragma unroll
    for (int r = 0; r < 4; r++) {
        const int e = blockIdx.x * 256 + tid + r * (NBLK2 * 256);
        short8 v = *(const short8*)(o2b + (size_t)e * 8);
        float4 o0, o1;
        o0.x = silu_f(a0 * bf2f(v[0]) + b0);
        o0.y = silu_f(a1 * bf2f(v[1]) + b1);
        o0.z = silu_f(a2 * bf2f(v[2]) + b2);
        o0.w = silu_f(a3 * bf2f(v[3]) + b3);
        o1.x = silu_f(a4 * bf2f(v[4]) + b4);
        o1.y = silu_f(a5 * bf2f(v[5]) + b5);
        o1.z = silu_f(a6 * bf2f(v[6]) + b6);
        o1.w = silu_f(a7 * bf2f(v[7]) + b7);
        *(float4*)(out + (size_t)e * 8)     = o0;
        *(float4*)(out + (size_t)e * 8 + 4) = o1;
    }
}

extern "C" void kernel_launch(void* const* d_in, const int* in_sizes, int n_in,
                              void* d_out, int out_size, void* d_ws, size_t ws_size,
                              hipStream_t stream)
{
    const int*   ij   = (const int*)d_in[0];
    const float* fn   = (const float*)d_in[1];
    const float* W0   = (const float*)d_in[2];
    const float* W1   = (const float*)d_in[3];
    const float* g1   = (const float*)d_in[4];
    const float* b1   = (const float*)d_in[5];
    const float* g2   = (const float*)d_in[6];
    const float* b2   = (const float*)d_in[7];
    const int*   norm = (const int*)d_in[8];
    float* out = (float*)d_out;

    float* p1  = (float*)d_ws;              // 512*64
    float* p2  = p1 + NBLK * 64;            // 512*16
    short* o2b = (short*)(p2 + NBLK * 16);  // E*8 bf16 (4 MB)

    nep_main<0><<<NBLK, TPB, 0, stream>>>(ij, fn, W0, W1, g1, b1, norm, nullptr, p1, nullptr);
    nep_main<1><<<NBLK, TPB, 0, stream>>>(ij, fn, W0, W1, g1, b1, norm, p1, p2, o2b);
    nep_bn2f<<<NBLK2, 256, 0, stream>>>(o2b, p2, g2, b2, norm, out);
}